// Round 3
// baseline (119.346 us; speedup 1.0000x reference)
//
#include <hip/hip_runtime.h>
#include <hip/hip_bf16.h>

#define N_LATENT 64
#define N_OUT    64

// One 64-lane wave per batch row. lane = output column.
// out[b,o] = u[b,o] + sum_d u[b,d]*A[sid[b],d,o] + offsets[sid[b],o]
__global__ __launch_bounds__(256) void linear_decoder_uz_kernel(
    const float* __restrict__ u,
    const int*   __restrict__ sample_id,
    const float* __restrict__ amat,
    const float* __restrict__ offsets,
    float*       __restrict__ out,
    int batch)
{
    const int gtid = blockIdx.x * blockDim.x + threadIdx.x;
    const int b    = gtid >> 6;          // wave index = row
    const int lane = threadIdx.x & 63;   // output column
    if (b >= batch) return;

    const int s = sample_id[b];

    // Each lane loads its own u element; full row broadcast via shfl.
    const float uv = u[(size_t)b * N_LATENT + lane];

    const float* __restrict__ Ab = amat + (size_t)s * (N_LATENT * N_OUT);
    float acc = offsets[(size_t)s * N_OUT + lane];

#pragma unroll
    for (int d = 0; d < N_LATENT; ++d) {
        const float ud = __shfl(uv, d, 64);          // broadcast u[b,d]
        acc = fmaf(ud, Ab[d * N_OUT + lane], acc);   // coalesced A row read
    }

    out[(size_t)b * N_OUT + lane] = uv + acc;
}

extern "C" void kernel_launch(void* const* d_in, const int* in_sizes, int n_in,
                              void* d_out, int out_size, void* d_ws, size_t ws_size,
                              hipStream_t stream)
{
    const float* u       = (const float*)d_in[0];
    const int*   sid     = (const int*)d_in[1];
    const float* amat    = (const float*)d_in[2];
    const float* offsets = (const float*)d_in[3];
    float*       out     = (float*)d_out;

    const int batch = in_sizes[0] / N_LATENT;   // 65536

    const int threads = 256;                    // 4 waves/block -> 4 rows/block
    const int rows_per_block = threads / 64;
    const int blocks = (batch + rows_per_block - 1) / rows_per_block;

    linear_decoder_uz_kernel<<<blocks, threads, 0, stream>>>(
        u, sid, amat, offsets, out, batch);
}

// Round 4
// 70.692 us; speedup vs baseline: 1.6883x; 1.6883x over previous
//
#include <hip/hip_runtime.h>
#include <hip/hip_bf16.h>

#define N_LATENT 64
#define N_OUT    64

// ---------------- Phase 0: zero the histogram counters ----------------
__global__ void zero_kernel(int* __restrict__ counts, int n)
{
    int i = blockIdx.x * blockDim.x + threadIdx.x;
    if (i < n) counts[i] = 0;
}

// ---------------- Phase 1: histogram of sample ids ----------------
__global__ void hist_kernel(const int* __restrict__ sid, int* __restrict__ counts, int n)
{
    int i = blockIdx.x * blockDim.x + threadIdx.x;
    if (i < n) atomicAdd(&counts[sid[i]], 1);
}

// ---------------- Phase 2: exclusive prefix sum (single block) ----------------
// counts[0..n_sample) -> starts[0..n_sample] (exclusive, starts[n_sample]=total)
// cursor[] initialized to starts[] for the scatter phase.
__global__ __launch_bounds__(1024) void scan_kernel(
    const int* __restrict__ counts,
    int* __restrict__ starts,
    int* __restrict__ cursor,
    int n_sample)
{
    __shared__ int tmp[1024];
    const int t = threadIdx.x;
    int v = (t < n_sample) ? counts[t] : 0;
    tmp[t] = v;
    __syncthreads();
    // Hillis-Steele inclusive scan
    for (int ofs = 1; ofs < 1024; ofs <<= 1) {
        int add = (t >= ofs) ? tmp[t - ofs] : 0;
        __syncthreads();
        tmp[t] += add;
        __syncthreads();
    }
    if (t < n_sample) {
        int excl = (t == 0) ? 0 : tmp[t - 1];
        starts[t] = excl;
        cursor[t] = excl;
        if (t == n_sample - 1) starts[n_sample] = tmp[t];
    }
}

// ---------------- Phase 3: scatter row indices into sid buckets ----------------
__global__ void scatter_kernel(const int* __restrict__ sid,
                               int* __restrict__ cursor,
                               int* __restrict__ perm, int n)
{
    int i = blockIdx.x * blockDim.x + threadIdx.x;
    if (i < n) {
        int p = atomicAdd(&cursor[sid[i]], 1);
        perm[p] = i;
    }
}

// ---------------- Phase 4: per-sid compute, A held in VGPRs ----------------
// One block per sample id. 4 waves/block; each wave processes rows of the
// bucket with stride 4. lane = output column. A column 'lane' lives in 64
// VGPRs; u[b,d] broadcast via v_readlane (VALU only, no LDS).
__global__ __launch_bounds__(256) void compute_kernel(
    const float* __restrict__ u,
    const float* __restrict__ amat,
    const float* __restrict__ offsets,
    const int*   __restrict__ starts,
    const int*   __restrict__ perm,
    float*       __restrict__ out)
{
    const int s    = blockIdx.x;          // sample id
    const int lane = threadIdx.x & 63;    // output column
    const int wave = threadIdx.x >> 6;    // 0..3

    const float* __restrict__ A = amat + (size_t)s * (N_LATENT * N_OUT);

    // Load A[:, lane] into registers (64 coalesced 256B reads, shared by
    // all 4 waves via L1/L2 -> A fetched ~once per sid from memory).
    float a[N_LATENT];
#pragma unroll
    for (int d = 0; d < N_LATENT; ++d) a[d] = A[d * N_OUT + lane];

    const float off = offsets[(size_t)s * N_OUT + lane];

    const int r0 = starts[s];
    const int r1 = starts[s + 1];

    for (int i = r0 + wave; i < r1; i += 4) {
        const int b = perm[i];                       // wave-uniform
        const float uv = u[(size_t)b * N_LATENT + lane];
        float acc = off;
#pragma unroll
        for (int d = 0; d < N_LATENT; ++d) {
            const float ud = __int_as_float(
                __builtin_amdgcn_readlane(__float_as_int(uv), d));
            acc = fmaf(ud, a[d], acc);
        }
        out[(size_t)b * N_OUT + lane] = uv + acc;
    }
}

extern "C" void kernel_launch(void* const* d_in, const int* in_sizes, int n_in,
                              void* d_out, int out_size, void* d_ws, size_t ws_size,
                              hipStream_t stream)
{
    const float* u       = (const float*)d_in[0];
    const int*   sid     = (const int*)d_in[1];
    const float* amat    = (const float*)d_in[2];
    const float* offsets = (const float*)d_in[3];
    float*       out     = (float*)d_out;

    const int batch    = in_sizes[0] / N_LATENT;            // 65536
    const int n_sample = in_sizes[2] / (N_LATENT * N_OUT);  // 1000

    // workspace layout (ints): [0,1024) counts | [1024,2048) starts(+total)
    //                          | [2048,3072) cursor | [3072, 3072+batch) perm
    int* w      = (int*)d_ws;
    int* counts = w;
    int* starts = w + 1024;
    int* cursor = w + 2048;
    int* perm   = w + 3072;

    zero_kernel<<<(n_sample + 255) / 256, 256, 0, stream>>>(counts, n_sample);
    hist_kernel<<<(batch + 255) / 256, 256, 0, stream>>>(sid, counts, batch);
    scan_kernel<<<1, 1024, 0, stream>>>(counts, starts, cursor, n_sample);
    scatter_kernel<<<(batch + 255) / 256, 256, 0, stream>>>(sid, cursor, perm, batch);
    compute_kernel<<<n_sample, 256, 0, stream>>>(u, amat, offsets, starts, perm, out);
}

// Round 6
// 48.155 us; speedup vs baseline: 2.4784x; 1.4680x over previous
//
#include <hip/hip_runtime.h>
#include <hip/hip_bf16.h>

#define N_LATENT 64
#define N_OUT    64

// One block per sample id s. Block holds A[s][:, lane] in 64 VGPRs per lane,
// scans the entire sid array (256 KB, L2-broadcast) with int4 loads + ballot,
// and computes every matching row in-place. Single kernel, no preprocessing.
__global__ __launch_bounds__(512) void decoder_scan_kernel(
    const float* __restrict__ u,
    const int*   __restrict__ sid,
    const float* __restrict__ amat,
    const float* __restrict__ offsets,
    float*       __restrict__ out,
    int batch)
{
    const int s      = blockIdx.x;          // sample id
    const int lane   = threadIdx.x & 63;    // output column
    const int wave   = threadIdx.x >> 6;    // 0..7
    const int nwaves = blockDim.x >> 6;     // 8

    // A column 'lane' into registers. All waves load the same 16 KB (L1-hit
    // after first wave); chip-wide A traffic = 16.4 MB (once per sid).
    const float* __restrict__ A = amat + (size_t)s * (N_LATENT * N_OUT);
    float a[N_LATENT];
#pragma unroll
    for (int d = 0; d < N_LATENT; ++d) a[d] = A[d * N_OUT + lane];

    const float off = offsets[(size_t)s * N_OUT + lane];

    // Each wave scans a contiguous slice of sid, 4 sids per lane per iter.
    const int4* __restrict__ sid4 = (const int4*)sid;
    const int n4       = batch >> 2;                       // batch % 4 == 0
    const int per_wave = (n4 + nwaves - 1) / nwaves;
    const int begin    = wave * per_wave;
    const int end      = (begin + per_wave < n4) ? (begin + per_wave) : n4;

    for (int c0 = begin; c0 < end; c0 += 64) {
        const int c = c0 + lane;
        int4 v;
        if (c < end) v = sid4[c];
        else         v = make_int4(-1, -1, -1, -1);

        unsigned long long m[4];
        m[0] = __ballot(v.x == s);
        m[1] = __ballot(v.y == s);
        m[2] = __ballot(v.z == s);
        m[3] = __ballot(v.w == s);

#pragma unroll
        for (int e = 0; e < 4; ++e) {
            unsigned long long mm = m[e];
            while (mm) {                       // wave-uniform loop
                const int j = __builtin_ctzll(mm);
                mm &= mm - 1;
                const int b = 4 * (c0 + j) + e;          // matching row
                const float uv = u[(size_t)b * N_LATENT + lane];
                float acc = off;
#pragma unroll
                for (int d = 0; d < N_LATENT; ++d) {
                    const float ud = __int_as_float(
                        __builtin_amdgcn_readlane(__float_as_int(uv), d));
                    acc = fmaf(ud, a[d], acc);
                }
                out[(size_t)b * N_OUT + lane] = uv + acc;
            }
        }
    }
}

extern "C" void kernel_launch(void* const* d_in, const int* in_sizes, int n_in,
                              void* d_out, int out_size, void* d_ws, size_t ws_size,
                              hipStream_t stream)
{
    const float* u       = (const float*)d_in[0];
    const int*   sid     = (const int*)d_in[1];
    const float* amat    = (const float*)d_in[2];
    const float* offsets = (const float*)d_in[3];
    float*       out     = (float*)d_out;

    const int batch    = in_sizes[0] / N_LATENT;            // 65536
    const int n_sample = in_sizes[2] / (N_LATENT * N_OUT);  // 1000

    decoder_scan_kernel<<<n_sample, 512, 0, stream>>>(
        u, sid, amat, offsets, out, batch);
}